// Round 11
// baseline (143.806 us; speedup 1.0000x reference)
//
#include <hip/hip_runtime.h>
#include <hip/hip_fp16.h>

#define N_NODES 50000
#define N_EDGES 800000
#define N_GRAPHS 1000
#define F_IN 128
#define HID 64
#define NBUCK 196          // ceil(N_NODES / 256)
#define BCAP 5120          // per-bucket region capacity (mean 4096)

typedef _Float16 half8 __attribute__((ext_vector_type(8)));
typedef float f32x4v __attribute__((ext_vector_type(4)));

__device__ __forceinline__ int wave_incl_scan_i(int v, int lane) {
  #pragma unroll
  for (int off = 1; off < 64; off <<= 1) {
    int t = __shfl_up(v, off, 64);
    if (lane >= off) v += t;
  }
  return v;
}

// ---------- prep: W2 -> transposed + XOR-swizzled fp16 global image ----------
// byte layout identical to the k_gg LDS tile: byte = (col<<7) + ((2k) ^ ((col&7)<<4))
__global__ void k_prep(const float* __restrict__ W, __half* __restrict__ wt16) {
  int i = blockIdx.x * 256 + threadIdx.x;
  if (i < 4096) {
    int k = i >> 6, col = i & 63;
    int boff = (col << 7) + ((k << 1) ^ ((col & 7) << 4));
    *(__half*)((char*)wt16 + boff) = __float2half(W[k * 64 + col]);
  }
}

// ---------- CSR build: phase A — bucket edges by dst>>8 (4-way split hist) ----------
__global__ __launch_bounds__(1024) void k_bucket(const int* __restrict__ src,
                                                 const int* __restrict__ dst,
                                                 int* __restrict__ bucket_cnt,
                                                 int2* __restrict__ region) {
  __shared__ int cnt4[4][NBUCK];   // counts, then per-copy stage bases
  __shared__ int gbase[NBUCK];     // block-local exclusive prefix
  __shared__ int gpos[NBUCK];      // global reservation
  __shared__ int tot[NBUCK];
  __shared__ int2 stage[4096];
  const int tid = threadIdx.x;
  const int copy = tid >> 8;       // 256-thread groups share a histogram copy
  for (int i = tid; i < 4 * NBUCK; i += 1024) ((int*)cnt4)[i] = 0;
  __syncthreads();
  int e0 = blockIdx.x * 4096;
  int2 rec0, rec1, rec2, rec3;
  int bk0 = -1, bk1 = -1, bk2 = -1, bk3 = -1;
  int rk0 = 0, rk1 = 0, rk2 = 0, rk3 = 0;
#define LOADA(i) { int e = e0 + tid + i * 1024;                                  \
    if (e < N_EDGES) { rec##i.x = src[e]; rec##i.y = dst[e];                     \
      bk##i = rec##i.y >> 8; rk##i = atomicAdd(&cnt4[copy][bk##i], 1); } }
  LOADA(0) LOADA(1) LOADA(2) LOADA(3)
#undef LOADA
  __syncthreads();
  if (tid < NBUCK)
    tot[tid] = cnt4[0][tid] + cnt4[1][tid] + cnt4[2][tid] + cnt4[3][tid];
  __syncthreads();
  if (tid < 64) {   // exclusive scan of tot[196] -> gbase
    int v0 = (tid * 4 + 0 < NBUCK) ? tot[tid * 4 + 0] : 0;
    int v1 = (tid * 4 + 1 < NBUCK) ? tot[tid * 4 + 1] : 0;
    int v2 = (tid * 4 + 2 < NBUCK) ? tot[tid * 4 + 2] : 0;
    int v3 = (tid * 4 + 3 < NBUCK) ? tot[tid * 4 + 3] : 0;
    int s = v0 + v1 + v2 + v3;
    int excl = wave_incl_scan_i(s, tid) - s;
    if (tid * 4 + 0 < NBUCK) gbase[tid * 4 + 0] = excl; excl += v0;
    if (tid * 4 + 1 < NBUCK) gbase[tid * 4 + 1] = excl; excl += v1;
    if (tid * 4 + 2 < NBUCK) gbase[tid * 4 + 2] = excl; excl += v2;
    if (tid * 4 + 3 < NBUCK) gbase[tid * 4 + 3] = excl;
  }
  __syncthreads();
  if (tid < NBUCK) {
    int b0 = gbase[tid];
    int c0 = cnt4[0][tid], c1 = cnt4[1][tid], c2 = cnt4[2][tid];
    cnt4[0][tid] = b0;
    cnt4[1][tid] = b0 + c0;
    cnt4[2][tid] = b0 + c0 + c1;
    cnt4[3][tid] = b0 + c0 + c1 + c2;
    int t = tot[tid];
    if (t > 0) gpos[tid] = atomicAdd(&bucket_cnt[tid], t);
  }
  __syncthreads();
  if (bk0 >= 0) stage[cnt4[copy][bk0] + rk0] = rec0;
  if (bk1 >= 0) stage[cnt4[copy][bk1] + rk1] = rec1;
  if (bk2 >= 0) stage[cnt4[copy][bk2] + rk2] = rec2;
  if (bk3 >= 0) stage[cnt4[copy][bk3] + rk3] = rec3;
  __syncthreads();
  int total = gbase[NBUCK - 1] + tot[NBUCK - 1];
  for (int j = tid; j < total; j += 1024) {
    int2 r = stage[j];
    int b = r.y >> 8;
    int k = gpos[b] + (j - gbase[b]);
    if (k < BCAP) region[b * BCAP + k] = r;
  }
}

// ---------- CSR build: phase B — per-bucket fine CSR (4-way hist, local bscan) ----------
__global__ __launch_bounds__(1024) void k_csr(const int2* __restrict__ region,
                                              const int* __restrict__ bucket_cnt,
                                              int* __restrict__ offs,
                                              float* __restrict__ dis,
                                              int* __restrict__ esrc) {
  __shared__ int sbase[NBUCK];
  __shared__ int h4[4][256];
  __shared__ int tot[256];
  __shared__ int base[256];
  __shared__ int stage[BCAP];
  const int b = blockIdx.x, tid = threadIdx.x;
  const int copy = tid >> 8;
  for (int i = tid; i < 1024; i += 1024) ((int*)h4)[i] = 0;
  if (tid < 64) {   // local exclusive scan of bucket_cnt[196] -> sbase
    int v0 = (tid * 4 + 0 < NBUCK) ? bucket_cnt[tid * 4 + 0] : 0;
    int v1 = (tid * 4 + 1 < NBUCK) ? bucket_cnt[tid * 4 + 1] : 0;
    int v2 = (tid * 4 + 2 < NBUCK) ? bucket_cnt[tid * 4 + 2] : 0;
    int v3 = (tid * 4 + 3 < NBUCK) ? bucket_cnt[tid * 4 + 3] : 0;
    int s = v0 + v1 + v2 + v3;
    int excl = wave_incl_scan_i(s, tid) - s;
    if (tid * 4 + 0 < NBUCK) sbase[tid * 4 + 0] = excl; excl += v0;
    if (tid * 4 + 1 < NBUCK) sbase[tid * 4 + 1] = excl; excl += v1;
    if (tid * 4 + 2 < NBUCK) sbase[tid * 4 + 2] = excl; excl += v2;
    if (tid * 4 + 3 < NBUCK) sbase[tid * 4 + 3] = excl;
  }
  __syncthreads();
  int cnt = bucket_cnt[b]; if (cnt > BCAP) cnt = BCAP;
  const int bbase = sbase[b];
  int rec0, rec1, rec2, rec3, rec4;
  int ln0 = -1, ln1 = -1, ln2 = -1, ln3 = -1, ln4 = -1;
  int rk0 = 0, rk1 = 0, rk2 = 0, rk3 = 0, rk4 = 0;
#define LOADB(i) { int j = tid + i * 1024;                                        \
    if (j < cnt) { int2 r = region[b * BCAP + j]; rec##i = r.x;                   \
      ln##i = r.y & 255; rk##i = atomicAdd(&h4[copy][ln##i], 1); } }
  LOADB(0) LOADB(1) LOADB(2) LOADB(3) LOADB(4)
#undef LOADB
  __syncthreads();
  if (tid < 256) tot[tid] = h4[0][tid] + h4[1][tid] + h4[2][tid] + h4[3][tid];
  __syncthreads();
  if (tid < 64) {   // exclusive scan of tot[256] -> base
    int v0 = tot[tid * 4 + 0], v1 = tot[tid * 4 + 1];
    int v2 = tot[tid * 4 + 2], v3 = tot[tid * 4 + 3];
    int s = v0 + v1 + v2 + v3;
    int excl = wave_incl_scan_i(s, tid) - s;
    base[tid * 4 + 0] = excl; excl += v0;
    base[tid * 4 + 1] = excl; excl += v1;
    base[tid * 4 + 2] = excl; excl += v2;
    base[tid * 4 + 3] = excl;
  }
  __syncthreads();
  if (tid < 256) {
    int node = b * 256 + tid;
    if (node < N_NODES) {
      offs[node] = bbase + base[tid];
      dis[node] = rsqrtf(1.0f + (float)tot[tid]);
    }
    int b0 = base[tid];
    int c0 = h4[0][tid], c1 = h4[1][tid], c2 = h4[2][tid];
    h4[0][tid] = b0;
    h4[1][tid] = b0 + c0;
    h4[2][tid] = b0 + c0 + c1;
    h4[3][tid] = b0 + c0 + c1 + c2;
  }
  if (b == 0 && tid == 0) offs[N_NODES] = N_EDGES;
  __syncthreads();
  if (ln0 >= 0) stage[h4[copy][ln0] + rk0] = rec0;
  if (ln1 >= 0) stage[h4[copy][ln1] + rk1] = rec1;
  if (ln2 >= 0) stage[h4[copy][ln2] + rk2] = rec2;
  if (ln3 >= 0) stage[h4[copy][ln3] + rk3] = rec3;
  if (ln4 >= 0) stage[h4[copy][ln4] + rk4] = rec4;
  __syncthreads();
  for (int j = tid; j < cnt; j += 1024) esrc[bbase + j] = stage[j];
}

// ---------- fp16 helpers ----------
__device__ __forceinline__ void acc8_fp16(float* acc, uint4 u) {
  float2 f;
  f = __half22float2(*(__half2*)&u.x); acc[0] += f.x; acc[1] += f.y;
  f = __half22float2(*(__half2*)&u.y); acc[2] += f.x; acc[3] += f.y;
  f = __half22float2(*(__half2*)&u.z); acc[4] += f.x; acc[5] += f.y;
  f = __half22float2(*(__half2*)&u.w); acc[6] += f.x; acc[7] += f.y;
}

// ---------- layer-1 GEMM via MFMA: T = fp16((X @ W1) * dis), X fp32 K=128 ----------
__global__ __launch_bounds__(256) void k_gemm1_mfma(const float* __restrict__ X,
                                                    const float* __restrict__ W,
                                                    const float* __restrict__ dis,
                                                    __half* __restrict__ T) {
  __shared__ __half wt[128 * 64];
  const int tid = threadIdx.x;
  for (int i = tid; i < 8192; i += 256) {
    int k = i >> 6, col = i & 63;
    int boff = (col << 8) + ((k << 1) ^ ((col & 7) << 4));
    *(__half*)((char*)wt + boff) = __float2half(W[k * 64 + col]);
  }
  __syncthreads();

  const int w = tid >> 6, l = tid & 63;
  const int row0 = blockIdx.x * 64 + w * 16;
  const int arow = row0 + (l & 15);
  const int koff = (l >> 4) << 3;

  half8 a[4];
  #pragma unroll
  for (int s = 0; s < 4; ++s) {
    half8 av = {};
    if (arow < N_NODES) {
      float4 f0 = *(const float4*)&X[arow * 128 + s * 32 + koff];
      float4 f1 = *(const float4*)&X[arow * 128 + s * 32 + koff + 4];
      av[0] = (_Float16)f0.x; av[1] = (_Float16)f0.y;
      av[2] = (_Float16)f0.z; av[3] = (_Float16)f0.w;
      av[4] = (_Float16)f1.x; av[5] = (_Float16)f1.y;
      av[6] = (_Float16)f1.z; av[7] = (_Float16)f1.w;
    }
    a[s] = av;
  }
  f32x4v acc[4] = {{0.f,0.f,0.f,0.f},{0.f,0.f,0.f,0.f},
                   {0.f,0.f,0.f,0.f},{0.f,0.f,0.f,0.f}};
  #pragma unroll
  for (int t = 0; t < 4; ++t) {
    int col = (t << 4) + (l & 15);
    #pragma unroll
    for (int s = 0; s < 4; ++s) {
      int kk = s * 32 + koff;
      half8 b = *(const half8*)((const char*)wt +
                 ((col << 8) + ((kk << 1) ^ ((col & 7) << 4))));
      acc[t] = __builtin_amdgcn_mfma_f32_16x16x32_f16(a[s], b, acc[t], 0, 0, 0);
    }
  }
  #pragma unroll
  for (int r = 0; r < 4; ++r) {
    int row = row0 + ((l >> 4) << 2) + r;
    if (row < N_NODES) {
      float dn = dis[row];
      #pragma unroll
      for (int t = 0; t < 4; ++t)
        T[row * 64 + (t << 4) + (l & 15)] = __float2half(acc[t][r] * dn);
    }
  }
}

// ---------- fused layer: gather (8 lanes/node) + relu -> LDS H -> MFMA GEMM ----------
// Block = 64 nodes / 512 threads. hs swizzled: byte = row*128 + ((2k) ^ ((row&7)<<4)).
__global__ __launch_bounds__(512) void k_gg(const __half* __restrict__ T,
                                            const int* __restrict__ offs,
                                            const int* __restrict__ esrc,
                                            const float* __restrict__ dis,
                                            const float* __restrict__ bias,
                                            const __half* __restrict__ wt16,
                                            __half* __restrict__ Tout) {
  __shared__ __half wt[64 * 64];   // W2^T swizzled fp16 (copied from global image)
  __shared__ __half hs[64 * 64];   // gathered H rows, swizzled
  const int tid = threadIdx.x;
  ((uint4*)wt)[tid] = ((const uint4*)wt16)[tid];   // 512 x 16B = 8 KB

  const int n0 = blockIdx.x * 64;
  const int nloc = tid >> 3;
  const int n = n0 + nloc;
  const int l8 = (tid & 7) << 3;
  uint4 hu = make_uint4(0u, 0u, 0u, 0u);
  if (n < N_NODES) {
    int e0 = offs[n], e1 = offs[n + 1];
    float acc[8] = {};
    acc8_fp16(acc, *(const uint4*)&T[n * 64 + l8]);   // self-loop (pre-scaled)
    int e = e0;
    for (; e + 8 <= e1; e += 8) {
      int s0 = esrc[e+0], s1 = esrc[e+1], s2 = esrc[e+2], s3 = esrc[e+3];
      int s4 = esrc[e+4], s5 = esrc[e+5], s6 = esrc[e+6], s7 = esrc[e+7];
      uint4 u0 = *(const uint4*)&T[s0 * 64 + l8];
      uint4 u1 = *(const uint4*)&T[s1 * 64 + l8];
      uint4 u2 = *(const uint4*)&T[s2 * 64 + l8];
      uint4 u3 = *(const uint4*)&T[s3 * 64 + l8];
      uint4 u4 = *(const uint4*)&T[s4 * 64 + l8];
      uint4 u5 = *(const uint4*)&T[s5 * 64 + l8];
      uint4 u6 = *(const uint4*)&T[s6 * 64 + l8];
      uint4 u7 = *(const uint4*)&T[s7 * 64 + l8];
      acc8_fp16(acc, u0); acc8_fp16(acc, u1); acc8_fp16(acc, u2); acc8_fp16(acc, u3);
      acc8_fp16(acc, u4); acc8_fp16(acc, u5); acc8_fp16(acc, u6); acc8_fp16(acc, u7);
    }
    for (; e + 4 <= e1; e += 4) {
      int s0 = esrc[e+0], s1 = esrc[e+1], s2 = esrc[e+2], s3 = esrc[e+3];
      uint4 u0 = *(const uint4*)&T[s0 * 64 + l8];
      uint4 u1 = *(const uint4*)&T[s1 * 64 + l8];
      uint4 u2 = *(const uint4*)&T[s2 * 64 + l8];
      uint4 u3 = *(const uint4*)&T[s3 * 64 + l8];
      acc8_fp16(acc, u0); acc8_fp16(acc, u1); acc8_fp16(acc, u2); acc8_fp16(acc, u3);
    }
    for (; e < e1; ++e) {
      acc8_fp16(acc, *(const uint4*)&T[esrc[e] * 64 + l8]);
    }
    float dn = dis[n];
    float4 b0 = *(const float4*)&bias[l8];
    float4 b1 = *(const float4*)&bias[l8 + 4];
    __half2 h0 = __floats2half2_rn(fmaxf(fmaf(dn, acc[0], b0.x), 0.f),
                                   fmaxf(fmaf(dn, acc[1], b0.y), 0.f));
    __half2 h1 = __floats2half2_rn(fmaxf(fmaf(dn, acc[2], b0.z), 0.f),
                                   fmaxf(fmaf(dn, acc[3], b0.w), 0.f));
    __half2 h2 = __floats2half2_rn(fmaxf(fmaf(dn, acc[4], b1.x), 0.f),
                                   fmaxf(fmaf(dn, acc[5], b1.y), 0.f));
    __half2 h3 = __floats2half2_rn(fmaxf(fmaf(dn, acc[6], b1.z), 0.f),
                                   fmaxf(fmaf(dn, acc[7], b1.w), 0.f));
    hu = make_uint4(*(unsigned*)&h0, *(unsigned*)&h1,
                    *(unsigned*)&h2, *(unsigned*)&h3);
  }
  *(uint4*)((char*)hs + ((nloc << 7) + ((l8 << 1) ^ ((nloc & 7) << 4)))) = hu;
  __syncthreads();

  // MFMA: 8 waves cover 64 rows x 64 cols (wave: rows 16*(w>>1), cols 32*(w&1))
  const int w = tid >> 6, l = tid & 63;
  const int rt = (w >> 1) << 4;
  const int ct0 = (w & 1) << 1;
  const int arowl = rt + (l & 15);
  const int koff = (l >> 4) << 3;
  half8 a0 = *(const half8*)((const char*)hs +
              ((arowl << 7) + ((koff << 1) ^ ((arowl & 7) << 4))));
  half8 a1 = *(const half8*)((const char*)hs +
              ((arowl << 7) + (((koff + 32) << 1) ^ ((arowl & 7) << 4))));
  f32x4v acc2[2] = {{0.f,0.f,0.f,0.f},{0.f,0.f,0.f,0.f}};
  #pragma unroll
  for (int t = 0; t < 2; ++t) {
    int col = ((ct0 + t) << 4) + (l & 15);
    half8 b0 = *(const half8*)((const char*)wt +
                ((col << 7) + ((koff << 1) ^ ((col & 7) << 4))));
    half8 b1 = *(const half8*)((const char*)wt +
                ((col << 7) + (((koff + 32) << 1) ^ ((col & 7) << 4))));
    acc2[t] = __builtin_amdgcn_mfma_f32_16x16x32_f16(a0, b0, acc2[t], 0, 0, 0);
    acc2[t] = __builtin_amdgcn_mfma_f32_16x16x32_f16(a1, b1, acc2[t], 0, 0, 0);
  }
  #pragma unroll
  for (int r = 0; r < 4; ++r) {
    int row = n0 + rt + ((l >> 4) << 2) + r;
    if (row < N_NODES) {
      float dn = dis[row];
      #pragma unroll
      for (int t = 0; t < 2; ++t)
        Tout[row * 64 + ((ct0 + t) << 4) + (l & 15)] = __float2half(acc2[t][r] * dn);
    }
  }
}

// ---------- final: gather + relu + dot(Wl) -> per-node scalar ----------
__global__ __launch_bounds__(256) void k_final(const __half* __restrict__ T,
                                               const int* __restrict__ offs,
                                               const int* __restrict__ esrc,
                                               const float* __restrict__ dis,
                                               const float* __restrict__ bias,
                                               const float* __restrict__ Wl,
                                               float* __restrict__ pern) {
  int tid = threadIdx.x;
  int n = blockIdx.x * 32 + (tid >> 3);
  int l8 = (tid & 7) << 3;
  if (n >= N_NODES) return;
  int e0 = offs[n], e1 = offs[n + 1];
  float acc[8] = {};
  acc8_fp16(acc, *(const uint4*)&T[n * 64 + l8]);
  int e = e0;
  for (; e + 8 <= e1; e += 8) {
    int s0 = esrc[e+0], s1 = esrc[e+1], s2 = esrc[e+2], s3 = esrc[e+3];
    int s4 = esrc[e+4], s5 = esrc[e+5], s6 = esrc[e+6], s7 = esrc[e+7];
    uint4 u0 = *(const uint4*)&T[s0 * 64 + l8];
    uint4 u1 = *(const uint4*)&T[s1 * 64 + l8];
    uint4 u2 = *(const uint4*)&T[s2 * 64 + l8];
    uint4 u3 = *(const uint4*)&T[s3 * 64 + l8];
    uint4 u4 = *(const uint4*)&T[s4 * 64 + l8];
    uint4 u5 = *(const uint4*)&T[s5 * 64 + l8];
    uint4 u6 = *(const uint4*)&T[s6 * 64 + l8];
    uint4 u7 = *(const uint4*)&T[s7 * 64 + l8];
    acc8_fp16(acc, u0); acc8_fp16(acc, u1); acc8_fp16(acc, u2); acc8_fp16(acc, u3);
    acc8_fp16(acc, u4); acc8_fp16(acc, u5); acc8_fp16(acc, u6); acc8_fp16(acc, u7);
  }
  for (; e + 4 <= e1; e += 4) {
    int s0 = esrc[e+0], s1 = esrc[e+1], s2 = esrc[e+2], s3 = esrc[e+3];
    uint4 u0 = *(const uint4*)&T[s0 * 64 + l8];
    uint4 u1 = *(const uint4*)&T[s1 * 64 + l8];
    uint4 u2 = *(const uint4*)&T[s2 * 64 + l8];
    uint4 u3 = *(const uint4*)&T[s3 * 64 + l8];
    acc8_fp16(acc, u0); acc8_fp16(acc, u1); acc8_fp16(acc, u2); acc8_fp16(acc, u3);
  }
  for (; e < e1; ++e) {
    acc8_fp16(acc, *(const uint4*)&T[esrc[e] * 64 + l8]);
  }
  float dn = dis[n];
  float4 b0 = *(const float4*)&bias[l8];
  float4 b1 = *(const float4*)&bias[l8 + 4];
  float4 w0 = *(const float4*)&Wl[l8];
  float4 w1 = *(const float4*)&Wl[l8 + 4];
  float s = fmaxf(fmaf(dn, acc[0], b0.x), 0.f) * w0.x
          + fmaxf(fmaf(dn, acc[1], b0.y), 0.f) * w0.y
          + fmaxf(fmaf(dn, acc[2], b0.z), 0.f) * w0.z
          + fmaxf(fmaf(dn, acc[3], b0.w), 0.f) * w0.w
          + fmaxf(fmaf(dn, acc[4], b1.x), 0.f) * w1.x
          + fmaxf(fmaf(dn, acc[5], b1.y), 0.f) * w1.y
          + fmaxf(fmaf(dn, acc[6], b1.z), 0.f) * w1.z
          + fmaxf(fmaf(dn, acc[7], b1.w), 0.f) * w1.w;
  s += __shfl_xor(s, 1, 64);
  s += __shfl_xor(s, 2, 64);
  s += __shfl_xor(s, 4, 64);
  if ((tid & 7) == 0) pern[n] = s;
}

// ---------- per-graph mean of per-node scalars + bl ----------
__global__ __launch_bounds__(64) void k_pool2(const float* __restrict__ pern,
                                              const int* __restrict__ batch,
                                              const float* __restrict__ bl,
                                              float* __restrict__ out) {
  int g = blockIdx.x;
  int lane = threadIdx.x;
  int lo = 0, hi = N_NODES;
  while (lo < hi) { int mid = (lo + hi) >> 1; if (batch[mid] < g) lo = mid + 1; else hi = mid; }
  int start = lo;
  hi = N_NODES;
  while (lo < hi) { int mid = (lo + hi) >> 1; if (batch[mid] < g + 1) lo = mid + 1; else hi = mid; }
  int end = lo;
  float acc = 0.f;
  for (int nn = start + lane; nn < end; nn += 64) acc += pern[nn];
  #pragma unroll
  for (int off = 32; off; off >>= 1) acc += __shfl_down(acc, off, 64);
  if (lane == 0) {
    float cntf = (float)(end - start);
    out[g] = acc / fmaxf(cntf, 1.0f) + bl[0];
  }
}

extern "C" void kernel_launch(void* const* d_in, const int* in_sizes, int n_in,
                              void* d_out, int out_size, void* d_ws, size_t ws_size,
                              hipStream_t stream) {
  const float* x    = (const float*)d_in[0];
  const float* W1   = (const float*)d_in[1];
  const float* b1   = (const float*)d_in[2];
  const float* W2   = (const float*)d_in[3];
  const float* b2   = (const float*)d_in[4];
  const float* Wl   = (const float*)d_in[5];
  const float* bl   = (const float*)d_in[6];
  const int*   eidx = (const int*)d_in[7];
  const int*   batch= (const int*)d_in[8];
  const int* e_src = eidx;             // edge_index[0]
  const int* e_dst = eidx + N_EDGES;   // edge_index[1]
  float* out = (float*)d_out;

  char* w = (char*)d_ws;
  size_t o = 0;
  auto alloc = [&](size_t bytes) { void* p = w + o; o += (bytes + 255) & ~(size_t)255; return p; };
  float*  dis    = (float*) alloc(N_NODES * 4);
  int*    offs   = (int*)   alloc((N_NODES + 1) * 4);
  int*    esrc   = (int*)   alloc((size_t)N_EDGES * 4);
  int*    bcnt   = (int*)   alloc(NBUCK * 4);
  int2*   region = (int2*)  alloc((size_t)NBUCK * BCAP * 8);
  __half* wt16   = (__half*)alloc(4096 * 2);
  __half* bufT   = (__half*)alloc((size_t)N_NODES * HID * 2);
  __half* bufU   = (__half*)alloc((size_t)N_NODES * HID * 2);
  float*  pern   = (float*) alloc(N_NODES * 4);

  const int NBG = (N_NODES + 63) / 64;   // 64-row blocks
  const int NGG = (N_NODES + 63) / 64;   // 64-node fused blocks
  const int NGA = (N_NODES + 31) / 32;   // 32-node final blocks

  (void)hipMemsetAsync(bcnt, 0, NBUCK * 4, stream);
  k_prep  <<<16, 256, 0, stream>>>(W2, wt16);
  k_bucket<<<(N_EDGES + 4095) / 4096, 1024, 0, stream>>>(e_src, e_dst, bcnt, region);
  k_csr   <<<NBUCK, 1024, 0, stream>>>(region, bcnt, offs, dis, esrc);

  k_gemm1_mfma<<<NBG, 256, 0, stream>>>(x, W1, dis, bufT);                    // -> T1
  k_gg  <<<NGG, 512, 0, stream>>>(bufT, offs, esrc, dis, b1, wt16, bufU);     // T1 -> T2
  k_gg  <<<NGG, 512, 0, stream>>>(bufU, offs, esrc, dis, b2, wt16, bufT);     // T2 -> T3
  k_gg  <<<NGG, 512, 0, stream>>>(bufT, offs, esrc, dis, b2, wt16, bufU);     // T3 -> T4
  k_gg  <<<NGG, 512, 0, stream>>>(bufU, offs, esrc, dis, b2, wt16, bufT);     // T4 -> T5
  k_final<<<NGA, 256, 0, stream>>>(bufT, offs, esrc, dis, b2, Wl, pern);
  k_pool2<<<N_GRAPHS, 64, 0, stream>>>(pern, batch, bl, out);
}

// Round 12
// 140.194 us; speedup vs baseline: 1.0258x; 1.0258x over previous
//
#include <hip/hip_runtime.h>
#include <hip/hip_fp16.h>

#define N_NODES 50000
#define N_EDGES 800000
#define N_GRAPHS 1000
#define F_IN 128
#define HID 64
#define NBUCK 196          // ceil(N_NODES / 256)
#define BCAP 5120          // per-bucket region capacity (mean 4096)

typedef _Float16 half8 __attribute__((ext_vector_type(8)));
typedef float f32x4v __attribute__((ext_vector_type(4)));

__device__ __forceinline__ int wave_incl_scan_i(int v, int lane) {
  #pragma unroll
  for (int off = 1; off < 64; off <<= 1) {
    int t = __shfl_up(v, off, 64);
    if (lane >= off) v += t;
  }
  return v;
}

// ---------- CSR build: phase A — bucket edges by dst>>8 (4-way split hist) ----------
__global__ __launch_bounds__(1024) void k_bucket(const int* __restrict__ src,
                                                 const int* __restrict__ dst,
                                                 int* __restrict__ bucket_cnt,
                                                 int2* __restrict__ region) {
  __shared__ int cnt4[4][NBUCK];
  __shared__ int gbase[NBUCK];
  __shared__ int gpos[NBUCK];
  __shared__ int tot[NBUCK];
  __shared__ int2 stage[4096];
  const int tid = threadIdx.x;
  const int copy = tid >> 8;
  for (int i = tid; i < 4 * NBUCK; i += 1024) ((int*)cnt4)[i] = 0;
  __syncthreads();
  int e0 = blockIdx.x * 4096;
  int2 rec0, rec1, rec2, rec3;
  int bk0 = -1, bk1 = -1, bk2 = -1, bk3 = -1;
  int rk0 = 0, rk1 = 0, rk2 = 0, rk3 = 0;
#define LOADA(i) { int e = e0 + tid + i * 1024;                                  \
    if (e < N_EDGES) { rec##i.x = src[e]; rec##i.y = dst[e];                     \
      bk##i = rec##i.y >> 8; rk##i = atomicAdd(&cnt4[copy][bk##i], 1); } }
  LOADA(0) LOADA(1) LOADA(2) LOADA(3)
#undef LOADA
  __syncthreads();
  if (tid < NBUCK)
    tot[tid] = cnt4[0][tid] + cnt4[1][tid] + cnt4[2][tid] + cnt4[3][tid];
  __syncthreads();
  if (tid < 64) {
    int v0 = (tid * 4 + 0 < NBUCK) ? tot[tid * 4 + 0] : 0;
    int v1 = (tid * 4 + 1 < NBUCK) ? tot[tid * 4 + 1] : 0;
    int v2 = (tid * 4 + 2 < NBUCK) ? tot[tid * 4 + 2] : 0;
    int v3 = (tid * 4 + 3 < NBUCK) ? tot[tid * 4 + 3] : 0;
    int s = v0 + v1 + v2 + v3;
    int excl = wave_incl_scan_i(s, tid) - s;
    if (tid * 4 + 0 < NBUCK) gbase[tid * 4 + 0] = excl; excl += v0;
    if (tid * 4 + 1 < NBUCK) gbase[tid * 4 + 1] = excl; excl += v1;
    if (tid * 4 + 2 < NBUCK) gbase[tid * 4 + 2] = excl; excl += v2;
    if (tid * 4 + 3 < NBUCK) gbase[tid * 4 + 3] = excl;
  }
  __syncthreads();
  if (tid < NBUCK) {
    int b0 = gbase[tid];
    int c0 = cnt4[0][tid], c1 = cnt4[1][tid], c2 = cnt4[2][tid];
    cnt4[0][tid] = b0;
    cnt4[1][tid] = b0 + c0;
    cnt4[2][tid] = b0 + c0 + c1;
    cnt4[3][tid] = b0 + c0 + c1 + c2;
    int t = tot[tid];
    if (t > 0) gpos[tid] = atomicAdd(&bucket_cnt[tid], t);
  }
  __syncthreads();
  if (bk0 >= 0) stage[cnt4[copy][bk0] + rk0] = rec0;
  if (bk1 >= 0) stage[cnt4[copy][bk1] + rk1] = rec1;
  if (bk2 >= 0) stage[cnt4[copy][bk2] + rk2] = rec2;
  if (bk3 >= 0) stage[cnt4[copy][bk3] + rk3] = rec3;
  __syncthreads();
  int total = gbase[NBUCK - 1] + tot[NBUCK - 1];
  for (int j = tid; j < total; j += 1024) {
    int2 r = stage[j];
    int b = r.y >> 8;
    int k = gpos[b] + (j - gbase[b]);
    if (k < BCAP) region[b * BCAP + k] = r;
  }
}

// ---------- CSR build: phase B — per-bucket fine CSR (4-way hist, local bscan) ----------
__global__ __launch_bounds__(1024) void k_csr(const int2* __restrict__ region,
                                              const int* __restrict__ bucket_cnt,
                                              int* __restrict__ offs,
                                              float* __restrict__ dis,
                                              int* __restrict__ esrc) {
  __shared__ int sbase[NBUCK];
  __shared__ int h4[4][256];
  __shared__ int tot[256];
  __shared__ int base[256];
  __shared__ int stage[BCAP];
  const int b = blockIdx.x, tid = threadIdx.x;
  const int copy = tid >> 8;
  for (int i = tid; i < 1024; i += 1024) ((int*)h4)[i] = 0;
  if (tid < 64) {
    int v0 = (tid * 4 + 0 < NBUCK) ? bucket_cnt[tid * 4 + 0] : 0;
    int v1 = (tid * 4 + 1 < NBUCK) ? bucket_cnt[tid * 4 + 1] : 0;
    int v2 = (tid * 4 + 2 < NBUCK) ? bucket_cnt[tid * 4 + 2] : 0;
    int v3 = (tid * 4 + 3 < NBUCK) ? bucket_cnt[tid * 4 + 3] : 0;
    int s = v0 + v1 + v2 + v3;
    int excl = wave_incl_scan_i(s, tid) - s;
    if (tid * 4 + 0 < NBUCK) sbase[tid * 4 + 0] = excl; excl += v0;
    if (tid * 4 + 1 < NBUCK) sbase[tid * 4 + 1] = excl; excl += v1;
    if (tid * 4 + 2 < NBUCK) sbase[tid * 4 + 2] = excl; excl += v2;
    if (tid * 4 + 3 < NBUCK) sbase[tid * 4 + 3] = excl;
  }
  __syncthreads();
  int cnt = bucket_cnt[b]; if (cnt > BCAP) cnt = BCAP;
  const int bbase = sbase[b];
  int rec0, rec1, rec2, rec3, rec4;
  int ln0 = -1, ln1 = -1, ln2 = -1, ln3 = -1, ln4 = -1;
  int rk0 = 0, rk1 = 0, rk2 = 0, rk3 = 0, rk4 = 0;
#define LOADB(i) { int j = tid + i * 1024;                                        \
    if (j < cnt) { int2 r = region[b * BCAP + j]; rec##i = r.x;                   \
      ln##i = r.y & 255; rk##i = atomicAdd(&h4[copy][ln##i], 1); } }
  LOADB(0) LOADB(1) LOADB(2) LOADB(3) LOADB(4)
#undef LOADB
  __syncthreads();
  if (tid < 256) tot[tid] = h4[0][tid] + h4[1][tid] + h4[2][tid] + h4[3][tid];
  __syncthreads();
  if (tid < 64) {
    int v0 = tot[tid * 4 + 0], v1 = tot[tid * 4 + 1];
    int v2 = tot[tid * 4 + 2], v3 = tot[tid * 4 + 3];
    int s = v0 + v1 + v2 + v3;
    int excl = wave_incl_scan_i(s, tid) - s;
    base[tid * 4 + 0] = excl; excl += v0;
    base[tid * 4 + 1] = excl; excl += v1;
    base[tid * 4 + 2] = excl; excl += v2;
    base[tid * 4 + 3] = excl;
  }
  __syncthreads();
  if (tid < 256) {
    int node = b * 256 + tid;
    if (node < N_NODES) {
      offs[node] = bbase + base[tid];
      dis[node] = rsqrtf(1.0f + (float)tot[tid]);
    }
    int b0 = base[tid];
    int c0 = h4[0][tid], c1 = h4[1][tid], c2 = h4[2][tid];
    h4[0][tid] = b0;
    h4[1][tid] = b0 + c0;
    h4[2][tid] = b0 + c0 + c1;
    h4[3][tid] = b0 + c0 + c1 + c2;
  }
  if (b == 0 && tid == 0) offs[N_NODES] = N_EDGES;
  __syncthreads();
  if (ln0 >= 0) stage[h4[copy][ln0] + rk0] = rec0;
  if (ln1 >= 0) stage[h4[copy][ln1] + rk1] = rec1;
  if (ln2 >= 0) stage[h4[copy][ln2] + rk2] = rec2;
  if (ln3 >= 0) stage[h4[copy][ln3] + rk3] = rec3;
  if (ln4 >= 0) stage[h4[copy][ln4] + rk4] = rec4;
  __syncthreads();
  for (int j = tid; j < cnt; j += 1024) esrc[bbase + j] = stage[j];
}

// ---------- fp16 helpers ----------
__device__ __forceinline__ void acc8_fp16(float* acc, uint4 u) {
  float2 f;
  f = __half22float2(*(__half2*)&u.x); acc[0] += f.x; acc[1] += f.y;
  f = __half22float2(*(__half2*)&u.y); acc[2] += f.x; acc[3] += f.y;
  f = __half22float2(*(__half2*)&u.z); acc[4] += f.x; acc[5] += f.y;
  f = __half22float2(*(__half2*)&u.w); acc[6] += f.x; acc[7] += f.y;
}

// ---------- layer-1 GEMM via MFMA: T = fp16((X @ W1) * dis), X fp32 K=128 ----------
__global__ __launch_bounds__(256) void k_gemm1_mfma(const float* __restrict__ X,
                                                    const float* __restrict__ W,
                                                    const float* __restrict__ dis,
                                                    __half* __restrict__ T) {
  __shared__ __half wt[128 * 64];
  const int tid = threadIdx.x;
  for (int i = tid; i < 8192; i += 256) {
    int k = i >> 6, col = i & 63;
    int boff = (col << 8) + ((k << 1) ^ ((col & 7) << 4));
    *(__half*)((char*)wt + boff) = __float2half(W[k * 64 + col]);
  }
  __syncthreads();

  const int w = tid >> 6, l = tid & 63;
  const int row0 = blockIdx.x * 64 + w * 16;
  const int arow = row0 + (l & 15);
  const int koff = (l >> 4) << 3;

  half8 a[4];
  #pragma unroll
  for (int s = 0; s < 4; ++s) {
    half8 av = {};
    if (arow < N_NODES) {
      float4 f0 = *(const float4*)&X[arow * 128 + s * 32 + koff];
      float4 f1 = *(const float4*)&X[arow * 128 + s * 32 + koff + 4];
      av[0] = (_Float16)f0.x; av[1] = (_Float16)f0.y;
      av[2] = (_Float16)f0.z; av[3] = (_Float16)f0.w;
      av[4] = (_Float16)f1.x; av[5] = (_Float16)f1.y;
      av[6] = (_Float16)f1.z; av[7] = (_Float16)f1.w;
    }
    a[s] = av;
  }
  f32x4v acc[4] = {{0.f,0.f,0.f,0.f},{0.f,0.f,0.f,0.f},
                   {0.f,0.f,0.f,0.f},{0.f,0.f,0.f,0.f}};
  __builtin_amdgcn_s_setprio(1);
  #pragma unroll
  for (int t = 0; t < 4; ++t) {
    int col = (t << 4) + (l & 15);
    #pragma unroll
    for (int s = 0; s < 4; ++s) {
      int kk = s * 32 + koff;
      half8 b = *(const half8*)((const char*)wt +
                 ((col << 8) + ((kk << 1) ^ ((col & 7) << 4))));
      acc[t] = __builtin_amdgcn_mfma_f32_16x16x32_f16(a[s], b, acc[t], 0, 0, 0);
    }
  }
  __builtin_amdgcn_s_setprio(0);
  #pragma unroll
  for (int r = 0; r < 4; ++r) {
    int row = row0 + ((l >> 4) << 2) + r;
    if (row < N_NODES) {
      float dn = dis[row];
      #pragma unroll
      for (int t = 0; t < 4; ++t)
        T[row * 64 + (t << 4) + (l & 15)] = __float2half(acc[t][r] * dn);
    }
  }
}

// ---------- fused layer: gather (8 lanes/node) + relu -> LDS H -> MFMA GEMM ----------
// Block = 32 nodes / 256 threads (R10 proven shape).
// hs swizzled: byte = row*128 + ((2k) ^ ((row&7)<<4)).
__global__ __launch_bounds__(256) void k_gg(const __half* __restrict__ T,
                                            const int* __restrict__ offs,
                                            const int* __restrict__ esrc,
                                            const float* __restrict__ dis,
                                            const float* __restrict__ bias,
                                            const float* __restrict__ W,
                                            __half* __restrict__ Tout) {
  __shared__ __half wt[64 * 64];   // W2^T swizzled fp16
  __shared__ __half hs[32 * 64];   // gathered H rows, swizzled
  const int tid = threadIdx.x;
  for (int i = tid; i < 4096; i += 256) {
    int k = i >> 6, col = i & 63;
    int boff = (col << 7) + ((k << 1) ^ ((col & 7) << 4));
    *(__half*)((char*)wt + boff) = __float2half(W[k * 64 + col]);
  }

  const int n0 = blockIdx.x * 32;
  const int nloc = tid >> 3;
  const int n = n0 + nloc;
  const int l8 = (tid & 7) << 3;
  uint4 hu = make_uint4(0u, 0u, 0u, 0u);
  if (n < N_NODES) {
    int e0 = offs[n], e1 = offs[n + 1];
    float acc[8] = {};
    acc8_fp16(acc, *(const uint4*)&T[n * 64 + l8]);   // self-loop (pre-scaled)
    int e = e0;
    for (; e + 8 <= e1; e += 8) {
      int s0 = esrc[e+0], s1 = esrc[e+1], s2 = esrc[e+2], s3 = esrc[e+3];
      int s4 = esrc[e+4], s5 = esrc[e+5], s6 = esrc[e+6], s7 = esrc[e+7];
      uint4 u0 = *(const uint4*)&T[s0 * 64 + l8];
      uint4 u1 = *(const uint4*)&T[s1 * 64 + l8];
      uint4 u2 = *(const uint4*)&T[s2 * 64 + l8];
      uint4 u3 = *(const uint4*)&T[s3 * 64 + l8];
      uint4 u4 = *(const uint4*)&T[s4 * 64 + l8];
      uint4 u5 = *(const uint4*)&T[s5 * 64 + l8];
      uint4 u6 = *(const uint4*)&T[s6 * 64 + l8];
      uint4 u7 = *(const uint4*)&T[s7 * 64 + l8];
      acc8_fp16(acc, u0); acc8_fp16(acc, u1); acc8_fp16(acc, u2); acc8_fp16(acc, u3);
      acc8_fp16(acc, u4); acc8_fp16(acc, u5); acc8_fp16(acc, u6); acc8_fp16(acc, u7);
    }
    for (; e + 4 <= e1; e += 4) {
      int s0 = esrc[e+0], s1 = esrc[e+1], s2 = esrc[e+2], s3 = esrc[e+3];
      uint4 u0 = *(const uint4*)&T[s0 * 64 + l8];
      uint4 u1 = *(const uint4*)&T[s1 * 64 + l8];
      uint4 u2 = *(const uint4*)&T[s2 * 64 + l8];
      uint4 u3 = *(const uint4*)&T[s3 * 64 + l8];
      acc8_fp16(acc, u0); acc8_fp16(acc, u1); acc8_fp16(acc, u2); acc8_fp16(acc, u3);
    }
    for (; e < e1; ++e) {
      acc8_fp16(acc, *(const uint4*)&T[esrc[e] * 64 + l8]);
    }
    float dn = dis[n];
    float4 b0 = *(const float4*)&bias[l8];
    float4 b1 = *(const float4*)&bias[l8 + 4];
    __half2 h0 = __floats2half2_rn(fmaxf(fmaf(dn, acc[0], b0.x), 0.f),
                                   fmaxf(fmaf(dn, acc[1], b0.y), 0.f));
    __half2 h1 = __floats2half2_rn(fmaxf(fmaf(dn, acc[2], b0.z), 0.f),
                                   fmaxf(fmaf(dn, acc[3], b0.w), 0.f));
    __half2 h2 = __floats2half2_rn(fmaxf(fmaf(dn, acc[4], b1.x), 0.f),
                                   fmaxf(fmaf(dn, acc[5], b1.y), 0.f));
    __half2 h3 = __floats2half2_rn(fmaxf(fmaf(dn, acc[6], b1.z), 0.f),
                                   fmaxf(fmaf(dn, acc[7], b1.w), 0.f));
    hu = make_uint4(*(unsigned*)&h0, *(unsigned*)&h1,
                    *(unsigned*)&h2, *(unsigned*)&h3);
  }
  *(uint4*)((char*)hs + ((nloc << 7) + ((l8 << 1) ^ ((nloc & 7) << 4)))) = hu;
  __syncthreads();

  // MFMA: 4 waves cover 32 rows x 64 cols (wave: rows 16*(w>>1), cols 32*(w&1))
  const int w = tid >> 6, l = tid & 63;
  const int rt = (w >> 1) << 4;
  const int ct0 = (w & 1) << 1;
  const int arowl = rt + (l & 15);
  const int koff = (l >> 4) << 3;
  half8 a0 = *(const half8*)((const char*)hs +
              ((arowl << 7) + ((koff << 1) ^ ((arowl & 7) << 4))));
  half8 a1 = *(const half8*)((const char*)hs +
              ((arowl << 7) + (((koff + 32) << 1) ^ ((arowl & 7) << 4))));
  f32x4v acc2[2] = {{0.f,0.f,0.f,0.f},{0.f,0.f,0.f,0.f}};
  __builtin_amdgcn_s_setprio(1);
  #pragma unroll
  for (int t = 0; t < 2; ++t) {
    int col = ((ct0 + t) << 4) + (l & 15);
    half8 b0 = *(const half8*)((const char*)wt +
                ((col << 7) + ((koff << 1) ^ ((col & 7) << 4))));
    half8 b1 = *(const half8*)((const char*)wt +
                ((col << 7) + (((koff + 32) << 1) ^ ((col & 7) << 4))));
    acc2[t] = __builtin_amdgcn_mfma_f32_16x16x32_f16(a0, b0, acc2[t], 0, 0, 0);
    acc2[t] = __builtin_amdgcn_mfma_f32_16x16x32_f16(a1, b1, acc2[t], 0, 0, 0);
  }
  __builtin_amdgcn_s_setprio(0);
  #pragma unroll
  for (int r = 0; r < 4; ++r) {
    int row = n0 + rt + ((l >> 4) << 2) + r;
    if (row < N_NODES) {
      float dn = dis[row];
      #pragma unroll
      for (int t = 0; t < 2; ++t)
        Tout[row * 64 + ((ct0 + t) << 4) + (l & 15)] = __float2half(acc2[t][r] * dn);
    }
  }
}

// ---------- final: gather + relu + dot(Wl) -> per-node scalar ----------
__global__ __launch_bounds__(256) void k_final(const __half* __restrict__ T,
                                               const int* __restrict__ offs,
                                               const int* __restrict__ esrc,
                                               const float* __restrict__ dis,
                                               const float* __restrict__ bias,
                                               const float* __restrict__ Wl,
                                               float* __restrict__ pern) {
  int tid = threadIdx.x;
  int n = blockIdx.x * 32 + (tid >> 3);
  int l8 = (tid & 7) << 3;
  if (n >= N_NODES) return;
  int e0 = offs[n], e1 = offs[n + 1];
  float acc[8] = {};
  acc8_fp16(acc, *(const uint4*)&T[n * 64 + l8]);
  int e = e0;
  for (; e + 8 <= e1; e += 8) {
    int s0 = esrc[e+0], s1 = esrc[e+1], s2 = esrc[e+2], s3 = esrc[e+3];
    int s4 = esrc[e+4], s5 = esrc[e+5], s6 = esrc[e+6], s7 = esrc[e+7];
    uint4 u0 = *(const uint4*)&T[s0 * 64 + l8];
    uint4 u1 = *(const uint4*)&T[s1 * 64 + l8];
    uint4 u2 = *(const uint4*)&T[s2 * 64 + l8];
    uint4 u3 = *(const uint4*)&T[s3 * 64 + l8];
    uint4 u4 = *(const uint4*)&T[s4 * 64 + l8];
    uint4 u5 = *(const uint4*)&T[s5 * 64 + l8];
    uint4 u6 = *(const uint4*)&T[s6 * 64 + l8];
    uint4 u7 = *(const uint4*)&T[s7 * 64 + l8];
    acc8_fp16(acc, u0); acc8_fp16(acc, u1); acc8_fp16(acc, u2); acc8_fp16(acc, u3);
    acc8_fp16(acc, u4); acc8_fp16(acc, u5); acc8_fp16(acc, u6); acc8_fp16(acc, u7);
  }
  for (; e + 4 <= e1; e += 4) {
    int s0 = esrc[e+0], s1 = esrc[e+1], s2 = esrc[e+2], s3 = esrc[e+3];
    uint4 u0 = *(const uint4*)&T[s0 * 64 + l8];
    uint4 u1 = *(const uint4*)&T[s1 * 64 + l8];
    uint4 u2 = *(const uint4*)&T[s2 * 64 + l8];
    uint4 u3 = *(const uint4*)&T[s3 * 64 + l8];
    acc8_fp16(acc, u0); acc8_fp16(acc, u1); acc8_fp16(acc, u2); acc8_fp16(acc, u3);
  }
  for (; e < e1; ++e) {
    acc8_fp16(acc, *(const uint4*)&T[esrc[e] * 64 + l8]);
  }
  float dn = dis[n];
  float4 b0 = *(const float4*)&bias[l8];
  float4 b1 = *(const float4*)&bias[l8 + 4];
  float4 w0 = *(const float4*)&Wl[l8];
  float4 w1 = *(const float4*)&Wl[l8 + 4];
  float s = fmaxf(fmaf(dn, acc[0], b0.x), 0.f) * w0.x
          + fmaxf(fmaf(dn, acc[1], b0.y), 0.f) * w0.y
          + fmaxf(fmaf(dn, acc[2], b0.z), 0.f) * w0.z
          + fmaxf(fmaf(dn, acc[3], b0.w), 0.f) * w0.w
          + fmaxf(fmaf(dn, acc[4], b1.x), 0.f) * w1.x
          + fmaxf(fmaf(dn, acc[5], b1.y), 0.f) * w1.y
          + fmaxf(fmaf(dn, acc[6], b1.z), 0.f) * w1.z
          + fmaxf(fmaf(dn, acc[7], b1.w), 0.f) * w1.w;
  s += __shfl_xor(s, 1, 64);
  s += __shfl_xor(s, 2, 64);
  s += __shfl_xor(s, 4, 64);
  if ((tid & 7) == 0) pern[n] = s;
}

// ---------- per-graph mean of per-node scalars + bl ----------
__global__ __launch_bounds__(64) void k_pool2(const float* __restrict__ pern,
                                              const int* __restrict__ batch,
                                              const float* __restrict__ bl,
                                              float* __restrict__ out) {
  int g = blockIdx.x;
  int lane = threadIdx.x;
  int lo = 0, hi = N_NODES;
  while (lo < hi) { int mid = (lo + hi) >> 1; if (batch[mid] < g) lo = mid + 1; else hi = mid; }
  int start = lo;
  hi = N_NODES;
  while (lo < hi) { int mid = (lo + hi) >> 1; if (batch[mid] < g + 1) lo = mid + 1; else hi = mid; }
  int end = lo;
  float acc = 0.f;
  for (int nn = start + lane; nn < end; nn += 64) acc += pern[nn];
  #pragma unroll
  for (int off = 32; off; off >>= 1) acc += __shfl_down(acc, off, 64);
  if (lane == 0) {
    float cntf = (float)(end - start);
    out[g] = acc / fmaxf(cntf, 1.0f) + bl[0];
  }
}

extern "C" void kernel_launch(void* const* d_in, const int* in_sizes, int n_in,
                              void* d_out, int out_size, void* d_ws, size_t ws_size,
                              hipStream_t stream) {
  const float* x    = (const float*)d_in[0];
  const float* W1   = (const float*)d_in[1];
  const float* b1   = (const float*)d_in[2];
  const float* W2   = (const float*)d_in[3];
  const float* b2   = (const float*)d_in[4];
  const float* Wl   = (const float*)d_in[5];
  const float* bl   = (const float*)d_in[6];
  const int*   eidx = (const int*)d_in[7];
  const int*   batch= (const int*)d_in[8];
  const int* e_src = eidx;             // edge_index[0]
  const int* e_dst = eidx + N_EDGES;   // edge_index[1]
  float* out = (float*)d_out;

  char* w = (char*)d_ws;
  size_t o = 0;
  auto alloc = [&](size_t bytes) { void* p = w + o; o += (bytes + 255) & ~(size_t)255; return p; };
  float*  dis    = (float*) alloc(N_NODES * 4);
  int*    offs   = (int*)   alloc((N_NODES + 1) * 4);
  int*    esrc   = (int*)   alloc((size_t)N_EDGES * 4);
  int*    bcnt   = (int*)   alloc(NBUCK * 4);
  int2*   region = (int2*)  alloc((size_t)NBUCK * BCAP * 8);
  __half* bufT   = (__half*)alloc((size_t)N_NODES * HID * 2);
  __half* bufU   = (__half*)alloc((size_t)N_NODES * HID * 2);
  float*  pern   = (float*) alloc(N_NODES * 4);

  const int NBG = (N_NODES + 63) / 64;   // 64-row blocks (layer-1 GEMM)
  const int NGA = (N_NODES + 31) / 32;   // 32-node blocks (fused/gather/final)

  (void)hipMemsetAsync(bcnt, 0, NBUCK * 4, stream);
  k_bucket<<<(N_EDGES + 4095) / 4096, 1024, 0, stream>>>(e_src, e_dst, bcnt, region);
  k_csr   <<<NBUCK, 1024, 0, stream>>>(region, bcnt, offs, dis, esrc);

  k_gemm1_mfma<<<NBG, 256, 0, stream>>>(x, W1, dis, bufT);                // -> T1
  k_gg  <<<NGA, 256, 0, stream>>>(bufT, offs, esrc, dis, b1, W2, bufU);   // T1 -> T2
  k_gg  <<<NGA, 256, 0, stream>>>(bufU, offs, esrc, dis, b2, W2, bufT);   // T2 -> T3
  k_gg  <<<NGA, 256, 0, stream>>>(bufT, offs, esrc, dis, b2, W2, bufU);   // T3 -> T4
  k_gg  <<<NGA, 256, 0, stream>>>(bufU, offs, esrc, dis, b2, W2, bufT);   // T4 -> T5
  k_final<<<NGA, 256, 0, stream>>>(bufT, offs, esrc, dis, b2, Wl, pern);
  k_pool2<<<N_GRAPHS, 64, 0, stream>>>(pern, batch, bl, out);
}